// Round 4
// baseline (315.753 us; speedup 1.0000x reference)
//
#include <hip/hip_runtime.h>
#include <cmath>

// ---------------------------------------------------------------------------
// Causal MHA. B=4, T=2048, C=1024, NH=16, HD=64.
//   0) cast x -> bf16; transpose-cast w_qkv, w_out -> bf16 [N,K]
//   1) qkv = xb @ wqkvT^T  via gemm256: 256x256 tile, BK=64, 8 waves,
//      4-phase pipelined schedule (T2 swizzle + counted vmcnt + T5 setprio).
//   1b) Vt[b,h][hd][T] = transpose of V
//   2) flash attention v8 = r0 pair-fused balanced grid + T12 in-register P
//      + dual-subtile ILP interleave + tree lsum + setprio. VGPR headroom is
//      free (grid-caps residency at 2 blocks/CU), spent on 2-stream ILP.
//   3) out = ctxb @ woutT^T + b_out (m97 128^2 GEMM, fp32 out)
// ---------------------------------------------------------------------------

typedef __bf16 bf16x4 __attribute__((ext_vector_type(4)));
typedef __bf16 bf16x8 __attribute__((ext_vector_type(8)));
typedef float  f32x4  __attribute__((ext_vector_type(4)));
typedef float  f32x16 __attribute__((ext_vector_type(16)));

__device__ __forceinline__ void gload_lds16(const __bf16* g, __bf16* l) {
    __builtin_amdgcn_global_load_lds(
        (const __attribute__((address_space(1))) void*)g,
        (__attribute__((address_space(3))) void*)l,
        16, 0, 0);
}

__device__ __forceinline__ unsigned packbf(float a, float b) {
    union { __bf16 h[2]; unsigned u; } t;
    t.h[0] = (__bf16)a; t.h[1] = (__bf16)b;
    return t.u;
}

// v_permlane32_swap_b32: a = [a.lo | b.lo], b = [a.hi | b.hi] (lane i <-> i+32)
__device__ __forceinline__ void permswap(unsigned& a, unsigned& b) {
    asm volatile("v_permlane32_swap_b32 %0, %1" : "+v"(a), "+v"(b));
}

#define BAR()  __builtin_amdgcn_s_barrier()
#define VM2()  { asm volatile("s_waitcnt vmcnt(2)" ::: "memory"); \
                 __builtin_amdgcn_sched_barrier(0); }

// ---- cast fp32 -> bf16, 4 elems/thread -------------------------------------
__global__ __launch_bounds__(256) void cast_bf16(const float* __restrict__ in,
                                                 __bf16* __restrict__ out, int n4) {
    int i = blockIdx.x * 256 + threadIdx.x;
    if (i >= n4) return;
    float4 f = *(const float4*)(in + (size_t)i * 4);
    bf16x4 o;
    o[0] = (__bf16)f.x; o[1] = (__bf16)f.y; o[2] = (__bf16)f.z; o[3] = (__bf16)f.w;
    *(bf16x4*)(out + (size_t)i * 4) = o;
}

// ---- transpose + cast: W[K,N] fp32 -> WT[N,K] bf16 -------------------------
__global__ __launch_bounds__(256) void transpose_cast(const float* __restrict__ W,
                                                      __bf16* __restrict__ WT,
                                                      int K, int N) {
    __shared__ float tile[32][33];
    const int n0 = blockIdx.x * 32, k0 = blockIdx.y * 32;
    const int tx = threadIdx.x & 31, ty = threadIdx.x >> 5;
    #pragma unroll
    for (int i = 0; i < 4; ++i)
        tile[ty + 8 * i][tx] = W[(size_t)(k0 + ty + 8 * i) * N + n0 + tx];
    __syncthreads();
    #pragma unroll
    for (int i = 0; i < 4; ++i)
        WT[(size_t)(n0 + ty + 8 * i) * K + k0 + tx] = (__bf16)tile[tx][ty + 8 * i];
}

// ---- V transpose: qkv V columns -> Vt[bh][hd=64][T=2048] -------------------
__global__ __launch_bounds__(256) void transpose_v(const __bf16* __restrict__ qkv,
                                                   __bf16* __restrict__ Vt) {
    constexpr int T = 2048, R3C = 3072;
    __shared__ __bf16 tile[64][72];
    const int bh = blockIdx.y;
    const int b  = bh >> 4, h = bh & 15;
    const int kt = blockIdx.x * 64;
    const int tid = threadIdx.x;
    #pragma unroll
    for (int i = 0; i < 2; ++i) {
        int idx = tid + 256 * i;
        int kr  = idx >> 3;
        int c8  = idx & 7;
        *(uint4*)&tile[kr][c8 * 8] =
            *(const uint4*)(qkv + (size_t)(b * T + kt + kr) * R3C + 2048 + h * 64 + c8 * 8);
    }
    __syncthreads();
    #pragma unroll
    for (int i = 0; i < 2; ++i) {
        int idx = tid + 256 * i;
        int d   = idx >> 3;
        int k8  = idx & 7;
        union { __bf16 v[8]; uint4 u; } t;
        #pragma unroll
        for (int j = 0; j < 8; ++j) t.v[j] = tile[k8 * 8 + j][d];
        *(uint4*)(Vt + ((size_t)bh * 64 + d) * T + kt + k8 * 8) = t.u;
    }
}

// ---------------------------------------------------------------------------
// gemm256: C[M,N] = A[M,K] @ BT[N,K]^T, bf16 out. 256x256 tile, BK=64,
// 512 threads = 8 waves (2M x 4N), wave tile 128x64, 16x16x32 MFMA.
// (unchanged from r3 -- see r3 comment block for schedule derivation)
// ---------------------------------------------------------------------------
__global__ __launch_bounds__(512) void gemm256(const __bf16* __restrict__ A,
                                               const __bf16* __restrict__ BT,
                                               __bf16* __restrict__ Cc,
                                               int M, int N, int K) {
    __shared__ __attribute__((aligned(16))) char lds[131072];
    const int tid = threadIdx.x, lane = tid & 63, w = tid >> 6;
    const int wr = w >> 2, wc = w & 3, cc = lane & 15, gg = lane >> 4;

    const int cpx = gridDim.x >> 3;
    const int swz = ((int)blockIdx.x & 7) * cpx + ((int)blockIdx.x >> 3);
    const int nbx = N >> 8;
    const int rowBase = (swz / nbx) << 8;
    const int colBase = (swz % nbx) << 8;
    const int NT = K >> 6;

    const int sChunk = (lane & 7) ^ (lane >> 3);
    const int rsub   = lane >> 3;

    auto stA = [&](int t, int h) {
        const int buf = t & 1, k0 = (t % NT) * 64;
        #pragma unroll
        for (int l = 0; l < 2; ++l) {
            int idx   = l * 8 + w;
            int rbase = ((idx >> 3) << 7) + h * 64 + ((idx & 7) << 3);
            gload_lds16(A + (size_t)(rowBase + rbase + rsub) * K + k0 + sChunk * 8,
                        (__bf16*)(lds + buf * 65536 + rbase * 128 + lane * 16));
        }
    };
    auto stB = [&](int t, int h) {
        const int buf = t & 1, k0 = (t % NT) * 64;
        #pragma unroll
        for (int l = 0; l < 2; ++l) {
            int idx   = l * 8 + w;
            int rbase = ((idx >> 2) << 6) + h * 32 + ((idx & 3) << 3);
            gload_lds16(BT + (size_t)(colBase + rbase + rsub) * K + k0 + sChunk * 8,
                        (__bf16*)(lds + buf * 65536 + 32768 + rbase * 128 + lane * 16));
        }
    };

    f32x4 acc[8][4];
    #pragma unroll
    for (int i = 0; i < 8; ++i)
        #pragma unroll
        for (int j = 0; j < 4; ++j) acc[i][j] = f32x4{0.f, 0.f, 0.f, 0.f};
    bf16x8 afr[8], bfr[8];

    auto rdA = [&](int buf, int mh) {
        const char* base = lds + buf * 65536;
        #pragma unroll
        for (int i = 0; i < 4; ++i)
            #pragma unroll
            for (int kk = 0; kk < 2; ++kk) {
                int r  = wr * 128 + mh * 64 + i * 16 + cc;
                int cb = (kk * 64 + gg * 16) ^ ((cc & 7) << 4);
                afr[i * 2 + kk] = *(const bf16x8*)(base + r * 128 + cb);
            }
    };
    auto rdB = [&](int buf) {
        const char* base = lds + buf * 65536 + 32768;
        #pragma unroll
        for (int j = 0; j < 4; ++j)
            #pragma unroll
            for (int kk = 0; kk < 2; ++kk) {
                int r  = wc * 64 + j * 16 + cc;
                int cb = (kk * 64 + gg * 16) ^ ((cc & 7) << 4);
                bfr[j * 2 + kk] = *(const bf16x8*)(base + r * 128 + cb);
            }
    };

#define QMFMA(MH, NH)                                                        \
    _Pragma("unroll") for (int i = 0; i < 4; ++i)                            \
    _Pragma("unroll") for (int j = 0; j < 2; ++j)                            \
    _Pragma("unroll") for (int kk = 0; kk < 2; ++kk)                         \
        acc[(MH)*4 + i][(NH)*2 + j] = __builtin_amdgcn_mfma_f32_16x16x32_bf16( \
            afr[i*2 + kk], bfr[((NH)*2 + j)*2 + kk], acc[(MH)*4 + i][(NH)*2 + j], 0, 0, 0);

    stA(0, 0); stB(0, 0); stA(0, 1); stB(0, 1); stA(1, 0);
    VM2(); BAR();

    for (int t = 0; t < NT; ++t) {
        const int buf = t & 1;
        rdA(buf, 0); rdB(buf);
        stB(t + 1, 0);
        BAR();
        __builtin_amdgcn_s_setprio(1); QMFMA(0, 0); __builtin_amdgcn_s_setprio(0);
        BAR();
        stA(t + 1, 1);
        BAR();
        __builtin_amdgcn_s_setprio(1); QMFMA(0, 1); __builtin_amdgcn_s_setprio(0);
        BAR();
        rdA(buf, 1);
        stB(t + 1, 1);
        BAR();
        __builtin_amdgcn_s_setprio(1); QMFMA(1, 0); __builtin_amdgcn_s_setprio(0);
        BAR();
        stA(t + 2, 0);
        BAR();
        __builtin_amdgcn_s_setprio(1); QMFMA(1, 1); __builtin_amdgcn_s_setprio(0);
        VM2(); BAR();
    }
#undef QMFMA

    #pragma unroll
    for (int i = 0; i < 8; ++i)
        #pragma unroll
        for (int j = 0; j < 4; ++j) {
            const int col = colBase + wc * 64 + j * 16 + cc;
            #pragma unroll
            for (int rr = 0; rr < 4; ++rr) {
                const int row = rowBase + wr * 128 + (i >> 2) * 64 + (i & 3) * 16 + gg * 4 + rr;
                Cc[(size_t)row * N + col] = (__bf16)acc[i][j][rr];
            }
        }
}

// ---------------------------------------------------------------------------
// m97-structure bf16 GEMM: C[M,N] = A[M,K] @ BT[N,K]^T (+bias). (out-proj)
// ---------------------------------------------------------------------------
template <typename OutT, bool BIAS>
__global__ __launch_bounds__(256) void gemm_bt(const __bf16* __restrict__ A,
                                               const __bf16* __restrict__ BT,
                                               OutT* __restrict__ Cc,
                                               const float* __restrict__ bias,
                                               int M, int N, int K) {
    __shared__ __bf16 As[128 * 32];
    __shared__ __bf16 Bs[128 * 32];

    const int tid  = threadIdx.x;
    const int lane = tid & 63;
    const int w    = tid >> 6;
    const int wr   = w >> 1, wc = w & 1;
    const int cc   = lane & 15, gg = lane >> 4;
    const int rowBase = blockIdx.y * 128;
    const int colBase = blockIdx.x * 128;

    f32x4 acc[4][4];
    #pragma unroll
    for (int i = 0; i < 4; ++i)
        #pragma unroll
        for (int j = 0; j < 4; ++j) acc[i][j] = f32x4{0.f, 0.f, 0.f, 0.f};

    for (int k0 = 0; k0 < K; k0 += 32) {
        __syncthreads();
        #pragma unroll
        for (int i = 0; i < 2; ++i) {
            int idx = tid + 256 * i;
            int r   = idx >> 2;
            int c4  = idx & 3;
            gload_lds16(A  + (size_t)(rowBase + r) * K + k0 + c4 * 8, &As[idx * 8]);
            gload_lds16(BT + (size_t)(colBase + r) * K + k0 + c4 * 8, &Bs[idx * 8]);
        }
        __syncthreads();

        bf16x8 af[4], bfr2[4];
        #pragma unroll
        for (int i = 0; i < 4; ++i)
            af[i] = *(const bf16x8*)&As[(wr * 64 + i * 16 + cc) * 32 + gg * 8];
        #pragma unroll
        for (int j = 0; j < 4; ++j)
            bfr2[j] = *(const bf16x8*)&Bs[(wc * 64 + j * 16 + cc) * 32 + gg * 8];
        #pragma unroll
        for (int i = 0; i < 4; ++i)
            #pragma unroll
            for (int j = 0; j < 4; ++j)
                acc[i][j] = __builtin_amdgcn_mfma_f32_16x16x32_bf16(af[i], bfr2[j], acc[i][j], 0, 0, 0);
    }

    #pragma unroll
    for (int i = 0; i < 4; ++i)
        #pragma unroll
        for (int j = 0; j < 4; ++j) {
            const int col = colBase + wc * 64 + j * 16 + cc;
            #pragma unroll
            for (int r = 0; r < 4; ++r) {
                const int row = rowBase + wr * 64 + i * 16 + gg * 4 + r;
                float v = acc[i][j][r];
                if (BIAS) v += bias[col];
                Cc[(size_t)row * N + col] = (OutT)v;
            }
        }
}

// ---------------------------------------------------------------------------
// MFMA flash attention v8 = pair-fused causal blocks (grid (64,8), uniform
// work) + T12 in-register P + DUAL-SUBTILE ILP: both 32-key halves of a
// 64-key staged tile are computed as two independent streams (8 QK MFMAs,
// 2x16 exps, 8 PV MFMAs per call) so the exp chain of one overlaps the
// MFMA/LDS latency of the other at 2 waves/SIMD. lsum is tree-reduced
// (depth 5, not 16). setprio(1) around MFMA clusters (T5, attn-positive).
// S^T = mfma(K_frag, Q_frag): col = q = lane&31,
//       row = key = (r&3) + 8*(r>>2) + 4*(lane>>5)   [guide m74/m101]
// ---------------------------------------------------------------------------
__global__ __launch_bounds__(256) void flash_attn_mfma(const __bf16* __restrict__ qkv,
                                                       const __bf16* __restrict__ Vt,
                                                       __bf16* __restrict__ ctx) {
    constexpr int T = 2048, C = 1024, HD = 64;
    constexpr int R3C = 3 * C;
    constexpr float K1 = 0.125f * 1.44269504088896f;   // scale * log2e
    constexpr float K2 = -16.0f * 1.44269504088896f;   // -M0 * log2e

    const int tid  = threadIdx.x;
    const int lane = tid & 63;
    const int w    = tid >> 6;
    const int q5   = lane & 31;
    const int half = lane >> 5;

    const int bh   = blockIdx.x;               // 0..63
    const int y    = blockIdx.y;               // 0..7
    const int qtA  = 15 - y;                   // heavy tile
    const int qtB  = y;                        // light tile (rides free)
    const int b    = bh >> 4;
    const int h    = bh & 15;
    const int srowA = qtA * 128 + w * 32;
    const int srowB = qtB * 128 + w * 32;
    const int ktmaxA = qtA * 128 + 64;
    const int ktmaxB = qtB * 128 + 64;

    __shared__ __attribute__((aligned(16))) __bf16 Ks [64][72];   // [key][hd]
    __shared__ __attribute__((aligned(16))) __bf16 VsT[64][72];   // [hd][key]

    const __bf16* QrowA = qkv + (size_t)(b * T + srowA + q5) * R3C + h * HD;
    const __bf16* QrowB = qkv + (size_t)(b * T + srowB + q5) * R3C + h * HD;
    bf16x8 QbA[4], QbB[4];
    #pragma unroll
    for (int ks = 0; ks < 4; ++ks) {
        QbA[ks] = *(const bf16x8*)(QrowA + ks * 16 + half * 8);
        QbB[ks] = *(const bf16x8*)(QrowB + ks * 16 + half * 8);
    }

    f32x16 OA[2], OB[2];
    #pragma unroll
    for (int mb = 0; mb < 2; ++mb)
        #pragma unroll
        for (int r = 0; r < 16; ++r) { OA[mb][r] = 0.f; OB[mb][r] = 0.f; }
    float lsumA = 0.f, lsumB = 0.f;

    const __bf16* Kb  = qkv + (size_t)(b * T) * R3C + C + h * HD;
    const __bf16* Vtb = Vt + (size_t)bh * 64 * T;

    for (int kt = 0; kt <= ktmaxA; kt += 64) {
        __syncthreads();
        #pragma unroll
        for (int i = 0; i < 2; ++i) {
            int idx = tid + 256 * i;
            int kr  = idx >> 3;
            int c8  = idx & 7;
            *(uint4*)&Ks[kr][c8 * 8] = *(const uint4*)(Kb + (size_t)(kt + kr) * R3C + c8 * 8);
        }
        #pragma unroll
        for (int i = 0; i < 2; ++i) {
            int idx = tid + 256 * i;
            int d   = idx >> 3;
            int k8  = idx & 7;
            *(uint4*)&VsT[d][k8 * 8] = *(const uint4*)(Vtb + (size_t)d * T + kt + k8 * 8);
        }
        __syncthreads();

        // both 32-key halves of the staged 64-key tile, as 2 ILP streams
        auto dual = [&](const bf16x8* Qb, int srow, f32x16* O, float& lsum) {
            bf16x8 kb0[4], kb1[4];
            #pragma unroll
            for (int ks = 0; ks < 4; ++ks) {
                kb0[ks] = *(const bf16x8*)&Ks[q5]     [ks * 16 + half * 8];
                kb1[ks] = *(const bf16x8*)&Ks[32 + q5][ks * 16 + half * 8];
            }
            f32x16 S0, S1;
            #pragma unroll
            for (int r = 0; r < 16; ++r) { S0[r] = 0.f; S1[r] = 0.f; }
            __builtin_amdgcn_s_setprio(1);
            #pragma unroll
            for (int ks = 0; ks < 4; ++ks) {
                S0 = __builtin_amdgcn_mfma_f32_32x32x16_bf16(kb0[ks], Qb[ks], S0, 0, 0, 0);
                S1 = __builtin_amdgcn_mfma_f32_32x32x16_bf16(kb1[ks], Qb[ks], S1, 0, 0, 0);
            }
            __builtin_amdgcn_s_setprio(0);
            if (kt + 31 > srow) {
                #pragma unroll
                for (int r = 0; r < 16; ++r) {
                    int key = kt + (r & 3) + 8 * (r >> 2) + 4 * half;
                    if (key > srow + q5) S0[r] = -1e30f;
                }
            }
            if (kt + 63 > srow) {
                #pragma unroll
                for (int r = 0; r < 16; ++r) {
                    int key = kt + 32 + (r & 3) + 8 * (r >> 2) + 4 * half;
                    if (key > srow + q5) S1[r] = -1e30f;
                }
            }
            float p0[16], p1[16];
            #pragma unroll
            for (int r = 0; r < 16; ++r) p0[r] = exp2f(fmaf(S0[r], K1, K2));
            #pragma unroll
            for (int r = 0; r < 16; ++r) p1[r] = exp2f(fmaf(S1[r], K1, K2));
            // tree lsum (depth 5) for both streams
            {
                float a0 = (p0[0] + p0[1]) + (p0[2] + p0[3]);
                float a1 = (p0[4] + p0[5]) + (p0[6] + p0[7]);
                float a2 = (p0[8] + p0[9]) + (p0[10] + p0[11]);
                float a3 = (p0[12] + p0[13]) + (p0[14] + p0[15]);
                float b0 = (p1[0] + p1[1]) + (p1[2] + p1[3]);
                float b1 = (p1[4] + p1[5]) + (p1[6] + p1[7]);
                float b2 = (p1[8] + p1[9]) + (p1[10] + p1[11]);
                float b3 = (p1[12] + p1[13]) + (p1[14] + p1[15]);
                lsum += ((a0 + a1) + (a2 + a3)) + ((b0 + b1) + (b2 + b3));
            }
            // T12 pack both streams
            unsigned u0 = packbf(p0[0],  p0[1]),  u1 = packbf(p0[2],  p0[3]);
            unsigned u2 = packbf(p0[4],  p0[5]),  u3 = packbf(p0[6],  p0[7]);
            permswap(u0, u2); permswap(u1, u3);
            unsigned u4 = packbf(p0[8],  p0[9]),  u5 = packbf(p0[10], p0[11]);
            unsigned u6 = packbf(p0[12], p0[13]), u7 = packbf(p0[14], p0[15]);
            permswap(u4, u6); permswap(u5, u7);
            unsigned v0 = packbf(p1[0],  p1[1]),  v1 = packbf(p1[2],  p1[3]);
            unsigned v2 = packbf(p1[4],  p1[5]),  v3 = packbf(p1[6],  p1[7]);
            permswap(v0, v2); permswap(v1, v3);
            unsigned v4 = packbf(p1[8],  p1[9]),  v5 = packbf(p1[10], p1[11]);
            unsigned v6 = packbf(p1[12], p1[13]), v7 = packbf(p1[14], p1[15]);
            permswap(v4, v6); permswap(v5, v7);
            union { unsigned u[4]; bf16x8 v; } pf00, pf01, pf10, pf11;
            pf00.u[0] = u0; pf00.u[1] = u1; pf00.u[2] = u2; pf00.u[3] = u3;
            pf01.u[0] = u4; pf01.u[1] = u5; pf01.u[2] = u6; pf01.u[3] = u7;
            pf10.u[0] = v0; pf10.u[1] = v1; pf10.u[2] = v2; pf10.u[3] = v3;
            pf11.u[0] = v4; pf11.u[1] = v5; pf11.u[2] = v6; pf11.u[3] = v7;
            __builtin_amdgcn_s_setprio(1);
            #pragma unroll
            for (int mb = 0; mb < 2; ++mb) {
                const __bf16* vrow = &VsT[mb * 32 + q5][half * 8];
                bf16x8 va = *(const bf16x8*)(vrow);
                O[mb] = __builtin_amdgcn_mfma_f32_32x32x16_bf16(va, pf00.v, O[mb], 0, 0, 0);
                bf16x8 vb = *(const bf16x8*)(vrow + 16);
                O[mb] = __builtin_amdgcn_mfma_f32_32x32x16_bf16(vb, pf01.v, O[mb], 0, 0, 0);
                bf16x8 vc = *(const bf16x8*)(vrow + 32);
                O[mb] = __builtin_amdgcn_mfma_f32_32x32x16_bf16(vc, pf10.v, O[mb], 0, 0, 0);
                bf16x8 vd = *(const bf16x8*)(vrow + 48);
                O[mb] = __builtin_amdgcn_mfma_f32_32x32x16_bf16(vd, pf11.v, O[mb], 0, 0, 0);
            }
            __builtin_amdgcn_s_setprio(0);
        };

        dual(QbA, srowA, OA, lsumA);
        if (kt <= ktmaxB) dual(QbB, srowB, OB, lsumB);
    }

    const float invA = 1.f / (lsumA + __shfl_xor(lsumA, 32));
    const float invB = 1.f / (lsumB + __shfl_xor(lsumB, 32));

    __bf16* crowA = ctx + (size_t)(b * T + srowA + q5) * C + h * HD;
    __bf16* crowB = ctx + (size_t)(b * T + srowB + q5) * C + h * HD;
    #pragma unroll
    for (int mb = 0; mb < 2; ++mb)
        #pragma unroll
        for (int a = 0; a < 4; ++a) {
            union { bf16x4 v; uint2 u; } pA, pB;
            #pragma unroll
            for (int bq = 0; bq < 4; ++bq) {
                pA.v[bq] = (__bf16)(OA[mb][4 * a + bq] * invA);
                pB.v[bq] = (__bf16)(OB[mb][4 * a + bq] * invB);
            }
            *(uint2*)(crowA + mb * 32 + 8 * a + 4 * half) = pA.u;
            *(uint2*)(crowB + mb * 32 + 8 * a + 4 * half) = pB.u;
        }
}

extern "C" void kernel_launch(void* const* d_in, const int* in_sizes, int n_in,
                              void* d_out, int out_size, void* d_ws, size_t ws_size,
                              hipStream_t stream) {
    constexpr int B = 4, T = 2048, C = 1024;
    constexpr int M = B * T;          // 8192

    const float* x     = (const float*)d_in[0];
    const float* w_qkv = (const float*)d_in[1];
    const float* w_out = (const float*)d_in[2];
    const float* b_out = (const float*)d_in[3];
    float* out = (float*)d_out;

    char* ws = (char*)d_ws;
    __bf16* xb     = (__bf16*)(ws);                      // 16 MB
    __bf16* wqkvT  = (__bf16*)(ws + (16ull << 20));      //  6 MB
    __bf16* woutT  = (__bf16*)(ws + (22ull << 20));      //  2 MB
    __bf16* qkvb   = (__bf16*)(ws + (24ull << 20));      // 48 MB
    __bf16* ctxb   = (__bf16*)(ws + (72ull << 20));      // 16 MB
    __bf16* Vt     = (__bf16*)(ws + (88ull << 20));      // 16 MB

    // 0) casts / transposes
    cast_bf16<<<(M * C / 4 + 255) / 256, 256, 0, stream>>>(x, xb, M * C / 4);
    transpose_cast<<<dim3(3 * C / 32, C / 32), 256, 0, stream>>>(w_qkv, wqkvT, C, 3 * C);
    transpose_cast<<<dim3(C / 32, C / 32), 256, 0, stream>>>(w_out, woutT, C, C);

    // 1) qkv = xb @ wqkvT^T  (bf16 out) -- 256^2 pipelined GEMM (384 blocks)
    gemm256<<<384, 512, 0, stream>>>(xb, wqkvT, qkvb, M, 3 * C, C);

    // 1b) V transpose
    transpose_v<<<dim3(T / 64, B * 16), 256, 0, stream>>>(qkvb, Vt);

    // 2) MFMA flash attention -> ctxb (pair-fused grid, dual-subtile ILP)
    flash_attn_mfma<<<dim3(B * 16, 8), 256, 0, stream>>>(qkvb, Vt, ctxb);

    // 3) out = ctxb @ woutT^T + b_out (fp32 out)
    gemm_bt<float, true><<<dim3(C / 128, M / 128), 256, 0, stream>>>(
        ctxb, woutT, out, b_out, M, C, C);
}

// Round 6
// 289.146 us; speedup vs baseline: 1.0920x; 1.0920x over previous
//
#include <hip/hip_runtime.h>
#include <cmath>

// ---------------------------------------------------------------------------
// Causal MHA. B=4, T=2048, C=1024, NH=16, HD=64.
//   0) cast x -> bf16; transpose-cast w_qkv, w_out -> bf16 [N,K]
//   1) qkv = xb @ wqkvT^T  via gemm256: 256x256 tile, BK=64, 8 waves,
//      4-phase pipelined schedule; r5: LDS swizzle switched from 3-bit
//      (col[6:4]^=row[2:0]) to the m201-verified st_16x32 (byte bit5 ^=
//      row bit2) -- isolated experiment, readable via total dur.
//      (r5 bench was an infra failure -- container acquisition; this is an
//      unchanged resubmit of the same experiment.)
//   1b) Vt[b,h][hd][T] = transpose of V
//   2) flash attention: EXACT r3 version (91 us, VGPR 124). r4 post-mortem:
//      dual-stream ILP pushed VGPR 124->136, crossed the 128 cliff,
//      occupancy halved (18->11%), dur 91->139. Flash MUST stay <=128 VGPR;
//      per-32-key subtile granularity is the proven operating point.
//   3) out = ctxb @ woutT^T + b_out (m97 128^2 GEMM, fp32 out)
// ---------------------------------------------------------------------------

typedef __bf16 bf16x4 __attribute__((ext_vector_type(4)));
typedef __bf16 bf16x8 __attribute__((ext_vector_type(8)));
typedef float  f32x4  __attribute__((ext_vector_type(4)));
typedef float  f32x16 __attribute__((ext_vector_type(16)));

__device__ __forceinline__ void gload_lds16(const __bf16* g, __bf16* l) {
    __builtin_amdgcn_global_load_lds(
        (const __attribute__((address_space(1))) void*)g,
        (__attribute__((address_space(3))) void*)l,
        16, 0, 0);
}

__device__ __forceinline__ unsigned packbf(float a, float b) {
    union { __bf16 h[2]; unsigned u; } t;
    t.h[0] = (__bf16)a; t.h[1] = (__bf16)b;
    return t.u;
}

// v_permlane32_swap_b32: a = [a.lo | b.lo], b = [a.hi | b.hi] (lane i <-> i+32)
__device__ __forceinline__ void permswap(unsigned& a, unsigned& b) {
    asm volatile("v_permlane32_swap_b32 %0, %1" : "+v"(a), "+v"(b));
}

#define BAR()  __builtin_amdgcn_s_barrier()
#define VM2()  { asm volatile("s_waitcnt vmcnt(2)" ::: "memory"); \
                 __builtin_amdgcn_sched_barrier(0); }

// ---- cast fp32 -> bf16, 4 elems/thread -------------------------------------
__global__ __launch_bounds__(256) void cast_bf16(const float* __restrict__ in,
                                                 __bf16* __restrict__ out, int n4) {
    int i = blockIdx.x * 256 + threadIdx.x;
    if (i >= n4) return;
    float4 f = *(const float4*)(in + (size_t)i * 4);
    bf16x4 o;
    o[0] = (__bf16)f.x; o[1] = (__bf16)f.y; o[2] = (__bf16)f.z; o[3] = (__bf16)f.w;
    *(bf16x4*)(out + (size_t)i * 4) = o;
}

// ---- transpose + cast: W[K,N] fp32 -> WT[N,K] bf16 -------------------------
__global__ __launch_bounds__(256) void transpose_cast(const float* __restrict__ W,
                                                      __bf16* __restrict__ WT,
                                                      int K, int N) {
    __shared__ float tile[32][33];
    const int n0 = blockIdx.x * 32, k0 = blockIdx.y * 32;
    const int tx = threadIdx.x & 31, ty = threadIdx.x >> 5;
    #pragma unroll
    for (int i = 0; i < 4; ++i)
        tile[ty + 8 * i][tx] = W[(size_t)(k0 + ty + 8 * i) * N + n0 + tx];
    __syncthreads();
    #pragma unroll
    for (int i = 0; i < 4; ++i)
        WT[(size_t)(n0 + ty + 8 * i) * K + k0 + tx] = (__bf16)tile[tx][ty + 8 * i];
}

// ---- V transpose: qkv V columns -> Vt[bh][hd=64][T=2048] -------------------
__global__ __launch_bounds__(256) void transpose_v(const __bf16* __restrict__ qkv,
                                                   __bf16* __restrict__ Vt) {
    constexpr int T = 2048, R3C = 3072;
    __shared__ __bf16 tile[64][72];
    const int bh = blockIdx.y;
    const int b  = bh >> 4, h = bh & 15;
    const int kt = blockIdx.x * 64;
    const int tid = threadIdx.x;
    #pragma unroll
    for (int i = 0; i < 2; ++i) {
        int idx = tid + 256 * i;
        int kr  = idx >> 3;
        int c8  = idx & 7;
        *(uint4*)&tile[kr][c8 * 8] =
            *(const uint4*)(qkv + (size_t)(b * T + kt + kr) * R3C + 2048 + h * 64 + c8 * 8);
    }
    __syncthreads();
    #pragma unroll
    for (int i = 0; i < 2; ++i) {
        int idx = tid + 256 * i;
        int d   = idx >> 3;
        int k8  = idx & 7;
        union { __bf16 v[8]; uint4 u; } t;
        #pragma unroll
        for (int j = 0; j < 8; ++j) t.v[j] = tile[k8 * 8 + j][d];
        *(uint4*)(Vt + ((size_t)bh * 64 + d) * T + kt + k8 * 8) = t.u;
    }
}

// ---------------------------------------------------------------------------
// gemm256: C[M,N] = A[M,K] @ BT[N,K]^T, bf16 out. 256x256 tile, BK=64,
// 512 threads = 8 waves (2M x 4N), wave tile 128x64, 16x16x32 MFMA.
// r5 change: LDS swizzle = m201-verified st_16x32 (byte bit5 ^= row bit2),
// applied via pre-swizzled global source chunk (write side) and XOR'd
// ds_read byte offset (read side). Schedule unchanged from r3.
// ---------------------------------------------------------------------------
__global__ __launch_bounds__(512) void gemm256(const __bf16* __restrict__ A,
                                               const __bf16* __restrict__ BT,
                                               __bf16* __restrict__ Cc,
                                               int M, int N, int K) {
    __shared__ __attribute__((aligned(16))) char lds[131072];
    const int tid = threadIdx.x, lane = tid & 63, w = tid >> 6;
    const int wr = w >> 2, wc = w & 3, cc = lane & 15, gg = lane >> 4;

    const int cpx = gridDim.x >> 3;
    const int swz = ((int)blockIdx.x & 7) * cpx + ((int)blockIdx.x >> 3);
    const int nbx = N >> 8;
    const int rowBase = (swz / nbx) << 8;
    const int colBase = (swz % nbx) << 8;
    const int NT = K >> 6;

    // st_16x32: LDS[r][c] = G[r][c ^ ((r>>2&1)<<5)].  Writing lane covers
    // row rbase+(lane>>3) (rbase%8==0) and chunk (lane&7); row bit2 of the
    // covered row = (lane>>5)&1 -> source chunk = (lane&7) ^ ((lane>>5)&1)<<1.
    const int sChunk = (lane & 7) ^ (((lane >> 5) & 1) << 1);
    const int rsub   = lane >> 3;

    auto stA = [&](int t, int h) {
        const int buf = t & 1, k0 = (t % NT) * 64;
        #pragma unroll
        for (int l = 0; l < 2; ++l) {
            int idx   = l * 8 + w;
            int rbase = ((idx >> 3) << 7) + h * 64 + ((idx & 7) << 3);
            gload_lds16(A + (size_t)(rowBase + rbase + rsub) * K + k0 + sChunk * 8,
                        (__bf16*)(lds + buf * 65536 + rbase * 128 + lane * 16));
        }
    };
    auto stB = [&](int t, int h) {
        const int buf = t & 1, k0 = (t % NT) * 64;
        #pragma unroll
        for (int l = 0; l < 2; ++l) {
            int idx   = l * 8 + w;
            int rbase = ((idx >> 2) << 6) + h * 32 + ((idx & 3) << 3);
            gload_lds16(BT + (size_t)(colBase + rbase + rsub) * K + k0 + sChunk * 8,
                        (__bf16*)(lds + buf * 65536 + 32768 + rbase * 128 + lane * 16));
        }
    };

    f32x4 acc[8][4];
    #pragma unroll
    for (int i = 0; i < 8; ++i)
        #pragma unroll
        for (int j = 0; j < 4; ++j) acc[i][j] = f32x4{0.f, 0.f, 0.f, 0.f};
    bf16x8 afr[8], bfr[8];

    // read row r = ...+cc: (r>>2)&1 = (cc>>2)&1 (other terms are %8==0)
    auto rdA = [&](int buf, int mh) {
        const char* base = lds + buf * 65536;
        #pragma unroll
        for (int i = 0; i < 4; ++i)
            #pragma unroll
            for (int kk = 0; kk < 2; ++kk) {
                int r  = wr * 128 + mh * 64 + i * 16 + cc;
                int cb = (kk * 64 + gg * 16) ^ (((cc >> 2) & 1) << 5);
                afr[i * 2 + kk] = *(const bf16x8*)(base + r * 128 + cb);
            }
    };
    auto rdB = [&](int buf) {
        const char* base = lds + buf * 65536 + 32768;
        #pragma unroll
        for (int j = 0; j < 4; ++j)
            #pragma unroll
            for (int kk = 0; kk < 2; ++kk) {
                int r  = wc * 64 + j * 16 + cc;
                int cb = (kk * 64 + gg * 16) ^ (((cc >> 2) & 1) << 5);
                bfr[j * 2 + kk] = *(const bf16x8*)(base + r * 128 + cb);
            }
    };

#define QMFMA(MH, NH)                                                        \
    _Pragma("unroll") for (int i = 0; i < 4; ++i)                            \
    _Pragma("unroll") for (int j = 0; j < 2; ++j)                            \
    _Pragma("unroll") for (int kk = 0; kk < 2; ++kk)                         \
        acc[(MH)*4 + i][(NH)*2 + j] = __builtin_amdgcn_mfma_f32_16x16x32_bf16( \
            afr[i*2 + kk], bfr[((NH)*2 + j)*2 + kk], acc[(MH)*4 + i][(NH)*2 + j], 0, 0, 0);

    stA(0, 0); stB(0, 0); stA(0, 1); stB(0, 1); stA(1, 0);
    VM2(); BAR();

    for (int t = 0; t < NT; ++t) {
        const int buf = t & 1;
        rdA(buf, 0); rdB(buf);
        stB(t + 1, 0);
        BAR();
        __builtin_amdgcn_s_setprio(1); QMFMA(0, 0); __builtin_amdgcn_s_setprio(0);
        BAR();
        stA(t + 1, 1);
        BAR();
        __builtin_amdgcn_s_setprio(1); QMFMA(0, 1); __builtin_amdgcn_s_setprio(0);
        BAR();
        rdA(buf, 1);
        stB(t + 1, 1);
        BAR();
        __builtin_amdgcn_s_setprio(1); QMFMA(1, 0); __builtin_amdgcn_s_setprio(0);
        BAR();
        stA(t + 2, 0);
        BAR();
        __builtin_amdgcn_s_setprio(1); QMFMA(1, 1); __builtin_amdgcn_s_setprio(0);
        VM2(); BAR();
    }
#undef QMFMA

    #pragma unroll
    for (int i = 0; i < 8; ++i)
        #pragma unroll
        for (int j = 0; j < 4; ++j) {
            const int col = colBase + wc * 64 + j * 16 + cc;
            #pragma unroll
            for (int rr = 0; rr < 4; ++rr) {
                const int row = rowBase + wr * 128 + (i >> 2) * 64 + (i & 3) * 16 + gg * 4 + rr;
                Cc[(size_t)row * N + col] = (__bf16)acc[i][j][rr];
            }
        }
}

// ---------------------------------------------------------------------------
// m97-structure bf16 GEMM: C[M,N] = A[M,K] @ BT[N,K]^T (+bias). (out-proj)
// ---------------------------------------------------------------------------
template <typename OutT, bool BIAS>
__global__ __launch_bounds__(256) void gemm_bt(const __bf16* __restrict__ A,
                                               const __bf16* __restrict__ BT,
                                               OutT* __restrict__ Cc,
                                               const float* __restrict__ bias,
                                               int M, int N, int K) {
    __shared__ __bf16 As[128 * 32];
    __shared__ __bf16 Bs[128 * 32];

    const int tid  = threadIdx.x;
    const int lane = tid & 63;
    const int w    = tid >> 6;
    const int wr   = w >> 1, wc = w & 1;
    const int cc   = lane & 15, gg = lane >> 4;
    const int rowBase = blockIdx.y * 128;
    const int colBase = blockIdx.x * 128;

    f32x4 acc[4][4];
    #pragma unroll
    for (int i = 0; i < 4; ++i)
        #pragma unroll
        for (int j = 0; j < 4; ++j) acc[i][j] = f32x4{0.f, 0.f, 0.f, 0.f};

    for (int k0 = 0; k0 < K; k0 += 32) {
        __syncthreads();
        #pragma unroll
        for (int i = 0; i < 2; ++i) {
            int idx = tid + 256 * i;
            int r   = idx >> 2;
            int c4  = idx & 3;
            gload_lds16(A  + (size_t)(rowBase + r) * K + k0 + c4 * 8, &As[idx * 8]);
            gload_lds16(BT + (size_t)(colBase + r) * K + k0 + c4 * 8, &Bs[idx * 8]);
        }
        __syncthreads();

        bf16x8 af[4], bfr2[4];
        #pragma unroll
        for (int i = 0; i < 4; ++i)
            af[i] = *(const bf16x8*)&As[(wr * 64 + i * 16 + cc) * 32 + gg * 8];
        #pragma unroll
        for (int j = 0; j < 4; ++j)
            bfr2[j] = *(const bf16x8*)&Bs[(wc * 64 + j * 16 + cc) * 32 + gg * 8];
        #pragma unroll
        for (int i = 0; i < 4; ++i)
            #pragma unroll
            for (int j = 0; j < 4; ++j)
                acc[i][j] = __builtin_amdgcn_mfma_f32_16x16x32_bf16(af[i], bfr2[j], acc[i][j], 0, 0, 0);
    }

    #pragma unroll
    for (int i = 0; i < 4; ++i)
        #pragma unroll
        for (int j = 0; j < 4; ++j) {
            const int col = colBase + wc * 64 + j * 16 + cc;
            #pragma unroll
            for (int r = 0; r < 4; ++r) {
                const int row = rowBase + wr * 64 + i * 16 + gg * 4 + r;
                float v = acc[i][j][r];
                if (BIAS) v += bias[col];
                Cc[(size_t)row * N + col] = (OutT)v;
            }
        }
}

// ---------------------------------------------------------------------------
// MFMA flash attention (EXACT r3 version): pair-fused causal blocks, grid
// (64,8), uniform 34 tile-computes per wave, T12 in-register P (no Ps LDS).
// S^T = mfma(K_frag, Q_frag): col = q = lane&31,
//       row = key = (r&3) + 8*(r>>2) + 4*(lane>>5)   [guide m74/m101]
// Fixed-max softmax p = exp2(s*0.125*log2e - 16*log2e); L per-lane + one
// shfl_xor(32) at the end. VGPR 124 -- keep below the 128 cliff (r4 lesson).
// ---------------------------------------------------------------------------
__global__ __launch_bounds__(256) void flash_attn_mfma(const __bf16* __restrict__ qkv,
                                                       const __bf16* __restrict__ Vt,
                                                       __bf16* __restrict__ ctx) {
    constexpr int T = 2048, C = 1024, HD = 64;
    constexpr int R3C = 3 * C;
    constexpr float K1 = 0.125f * 1.44269504088896f;   // scale * log2e
    constexpr float K2 = -16.0f * 1.44269504088896f;   // -M0 * log2e

    const int tid  = threadIdx.x;
    const int lane = tid & 63;
    const int w    = tid >> 6;
    const int q5   = lane & 31;
    const int half = lane >> 5;

    const int bh   = blockIdx.x;               // 0..63
    const int y    = blockIdx.y;               // 0..7
    const int qtA  = 15 - y;                   // heavy tile
    const int qtB  = y;                        // light tile (rides free)
    const int b    = bh >> 4;
    const int h    = bh & 15;
    const int srowA = qtA * 128 + w * 32;
    const int srowB = qtB * 128 + w * 32;
    const int ktmaxA = qtA * 128 + 64;
    const int ktmaxB = qtB * 128 + 64;

    __shared__ __attribute__((aligned(16))) __bf16 Ks [64][72];   // [key][hd]
    __shared__ __attribute__((aligned(16))) __bf16 VsT[64][72];   // [hd][key]

    const __bf16* QrowA = qkv + (size_t)(b * T + srowA + q5) * R3C + h * HD;
    const __bf16* QrowB = qkv + (size_t)(b * T + srowB + q5) * R3C + h * HD;
    bf16x8 QbA[4], QbB[4];
    #pragma unroll
    for (int ks = 0; ks < 4; ++ks) {
        QbA[ks] = *(const bf16x8*)(QrowA + ks * 16 + half * 8);
        QbB[ks] = *(const bf16x8*)(QrowB + ks * 16 + half * 8);
    }

    f32x16 OA[2], OB[2];
    #pragma unroll
    for (int mb = 0; mb < 2; ++mb)
        #pragma unroll
        for (int r = 0; r < 16; ++r) { OA[mb][r] = 0.f; OB[mb][r] = 0.f; }
    float lsumA = 0.f, lsumB = 0.f;

    const __bf16* Kb  = qkv + (size_t)(b * T) * R3C + C + h * HD;
    const __bf16* Vtb = Vt + (size_t)bh * 64 * T;

    for (int kt = 0; kt <= ktmaxA; kt += 64) {
        __syncthreads();
        #pragma unroll
        for (int i = 0; i < 2; ++i) {
            int idx = tid + 256 * i;
            int kr  = idx >> 3;
            int c8  = idx & 7;
            *(uint4*)&Ks[kr][c8 * 8] = *(const uint4*)(Kb + (size_t)(kt + kr) * R3C + c8 * 8);
        }
        #pragma unroll
        for (int i = 0; i < 2; ++i) {
            int idx = tid + 256 * i;
            int d   = idx >> 3;
            int k8  = idx & 7;
            *(uint4*)&VsT[d][k8 * 8] = *(const uint4*)(Vtb + (size_t)d * T + kt + k8 * 8);
        }
        __syncthreads();

        // one 32-key sub-tile: S -> mask -> exp -> T12 pack -> PV
        auto subtile = [&](int sub, const bf16x8* Qb, int srow, f32x16* O, float& lsum) {
            f32x16 S;
            #pragma unroll
            for (int r = 0; r < 16; ++r) S[r] = 0.f;
            #pragma unroll
            for (int ks = 0; ks < 4; ++ks) {
                bf16x8 kb = *(const bf16x8*)&Ks[sub * 32 + q5][ks * 16 + half * 8];
                S = __builtin_amdgcn_mfma_f32_32x32x16_bf16(kb, Qb[ks], S, 0, 0, 0);
            }
            if (kt + sub * 32 + 31 > srow) {
                #pragma unroll
                for (int r = 0; r < 16; ++r) {
                    int key = kt + sub * 32 + (r & 3) + 8 * (r >> 2) + 4 * half;
                    if (key > srow + q5) S[r] = -1e30f;
                }
            }
            float p[16];
            #pragma unroll
            for (int r = 0; r < 16; ++r) {
                p[r] = exp2f(fmaf(S[r], K1, K2));
                lsum += p[r];
            }
            unsigned w0 = packbf(p[0],  p[1]);
            unsigned w1 = packbf(p[2],  p[3]);
            unsigned w2 = packbf(p[4],  p[5]);
            unsigned w3 = packbf(p[6],  p[7]);
            permswap(w0, w2);
            permswap(w1, w3);
            unsigned w4 = packbf(p[8],  p[9]);
            unsigned w5 = packbf(p[10], p[11]);
            unsigned w6 = packbf(p[12], p[13]);
            unsigned w7 = packbf(p[14], p[15]);
            permswap(w4, w6);
            permswap(w5, w7);
            union { unsigned u[4]; bf16x8 v; } pf0, pf1;
            pf0.u[0] = w0; pf0.u[1] = w1; pf0.u[2] = w2; pf0.u[3] = w3;
            pf1.u[0] = w4; pf1.u[1] = w5; pf1.u[2] = w6; pf1.u[3] = w7;
            const int vc = sub * 32 + half * 8;
            #pragma unroll
            for (int mb = 0; mb < 2; ++mb) {
                bf16x8 v0 = *(const bf16x8*)&VsT[mb * 32 + q5][vc];
                O[mb] = __builtin_amdgcn_mfma_f32_32x32x16_bf16(v0, pf0.v, O[mb], 0, 0, 0);
                bf16x8 v1 = *(const bf16x8*)&VsT[mb * 32 + q5][vc + 16];
                O[mb] = __builtin_amdgcn_mfma_f32_32x32x16_bf16(v1, pf1.v, O[mb], 0, 0, 0);
            }
        };

        #pragma unroll
        for (int sub = 0; sub < 2; ++sub)
            subtile(sub, QbA, srowA, OA, lsumA);
        if (kt <= ktmaxB) {
            #pragma unroll
            for (int sub = 0; sub < 2; ++sub)
                subtile(sub, QbB, srowB, OB, lsumB);
        }
    }

    const float invA = 1.f / (lsumA + __shfl_xor(lsumA, 32));
    const float invB = 1.f / (lsumB + __shfl_xor(lsumB, 32));

    __bf16* crowA = ctx + (size_t)(b * T + srowA + q5) * C + h * HD;
    __bf16* crowB = ctx + (size_t)(b * T + srowB + q5) * C + h * HD;
    #pragma unroll
    for (int mb = 0; mb < 2; ++mb)
        #pragma unroll
        for (int a = 0; a < 4; ++a) {
            union { bf16x4 v; uint2 u; } pA, pB;
            #pragma unroll
            for (int bq = 0; bq < 4; ++bq) {
                pA.v[bq] = (__bf16)(OA[mb][4 * a + bq] * invA);
                pB.v[bq] = (__bf16)(OB[mb][4 * a + bq] * invB);
            }
            *(uint2*)(crowA + mb * 32 + 8 * a + 4 * half) = pA.u;
            *(uint2*)(crowB + mb * 32 + 8 * a + 4 * half) = pB.u;
        }
}

extern "C" void kernel_launch(void* const* d_in, const int* in_sizes, int n_in,
                              void* d_out, int out_size, void* d_ws, size_t ws_size,
                              hipStream_t stream) {
    constexpr int B = 4, T = 2048, C = 1024;
    constexpr int M = B * T;          // 8192

    const float* x     = (const float*)d_in[0];
    const float* w_qkv = (const float*)d_in[1];
    const float* w_out = (const float*)d_in[2];
    const float* b_out = (const float*)d_in[3];
    float* out = (float*)d_out;

    char* ws = (char*)d_ws;
    __bf16* xb     = (__bf16*)(ws);                      // 16 MB
    __bf16* wqkvT  = (__bf16*)(ws + (16ull << 20));      //  6 MB
    __bf16* woutT  = (__bf16*)(ws + (22ull << 20));      //  2 MB
    __bf16* qkvb   = (__bf16*)(ws + (24ull << 20));      // 48 MB
    __bf16* ctxb   = (__bf16*)(ws + (72ull << 20));      // 16 MB
    __bf16* Vt     = (__bf16*)(ws + (88ull << 20));      // 16 MB

    // 0) casts / transposes
    cast_bf16<<<(M * C / 4 + 255) / 256, 256, 0, stream>>>(x, xb, M * C / 4);
    transpose_cast<<<dim3(3 * C / 32, C / 32), 256, 0, stream>>>(w_qkv, wqkvT, C, 3 * C);
    transpose_cast<<<dim3(C / 32, C / 32), 256, 0, stream>>>(w_out, woutT, C, C);

    // 1) qkv = xb @ wqkvT^T  (bf16 out) -- 256^2 pipelined GEMM (384 blocks)
    gemm256<<<384, 512, 0, stream>>>(xb, wqkvT, qkvb, M, 3 * C, C);

    // 1b) V transpose
    transpose_v<<<dim3(T / 64, B * 16), 256, 0, stream>>>(qkvb, Vt);

    // 2) MFMA flash attention -> ctxb (r3 exact)
    flash_attn_mfma<<<dim3(B * 16, 8), 256, 0, stream>>>(qkvb, Vt, ctxb);

    // 3) out = ctxb @ woutT^T + b_out (fp32 out)
    gemm_bt<float, true><<<dim3(C / 128, M / 128), 256, 0, stream>>>(
        ctxb, woutT, out, b_out, M, C, C);
}